// Round 3
// baseline (382.561 us; speedup 1.0000x reference)
//
#include <hip/hip_runtime.h>
#include <stdint.h>

// SAGEConv via linearity: out = x@W1^T + b + mean_neigh(x)@W2^T
//                             = [x@W1^T + b] + mean_d( (x@W2^T)[e_d] )
// N=100000, MAX_DEG=16, D_IN=256, D_OUT=256
//
// R6: gather kernel's 8-deep staging had collapsed again (VGPR=40 -> only
// ~2 gathers in flight, latency-bound at 3.9 TB/s). Pin all 8 staged rows
// + prefetched out row live with empty-asm ("+v") after issue, so the
// compiler cannot re-fuse load+consume. 9 independent loads in flight/lane.

#define MAX_DEG 16
#define D_IN 256
#define D_OUT 256
#define N_NODES_C 100000
#define BM 64
#define LDS_A_STRIDE 264   // 256 + 8 pad (ushort elems); row stride 528 B

typedef __attribute__((ext_vector_type(8))) short bf16x8;   // 8 bf16 = 4 VGPRs
typedef __attribute__((ext_vector_type(4))) float f32x4;

__device__ __forceinline__ uint32_t f2bf(float f) {
    union { float f; uint32_t u; } v; v.f = f;
    uint32_t u = v.u;
    return (u + 0x7FFFu + ((u >> 16) & 1u)) >> 16;   // RNE; inputs finite
}
__device__ __forceinline__ uint32_t pack2(float lo, float hi) {
    return f2bf(lo) | (f2bf(hi) << 16);
}

// ---- cast W into fragment-major bf16 Wb2f[cg][ks][lane][8]:
//      c = cg*16 + (lane&15), k = ks*32 + (lane>>4)*8 + e
//      (c<256 -> W[c][k] self half; c>=256 -> W[c-256][256+k] neighbor half)
// ---- and zero y2 row N (padding row for edge index -1)
__global__ __launch_bounds__(256) void cast_w2f_kernel(
    const float* __restrict__ W, ushort* __restrict__ Wb2f, ushort* __restrict__ y2)
{
    if (blockIdx.x < 64) {
        const int t = blockIdx.x * 256 + threadIdx.x;   // 0..16383
        const int cg   = t >> 9;          // 0..31
        const int ks   = (t >> 6) & 7;    // 0..7
        const int lane = t & 63;
        const int quad = lane >> 4, r16 = lane & 15;
        const int c = cg * 16 + r16;      // 0..511
        const int k = ks * 32 + quad * 8;
        const float* src = W + (size_t)(c & 255) * 512 + (c >> 8) * 256 + k;
        float4 v0 = ((const float4*)src)[0];
        float4 v1 = ((const float4*)src)[1];
        uint4 p = { pack2(v0.x, v0.y), pack2(v0.z, v0.w),
                    pack2(v1.x, v1.y), pack2(v1.z, v1.w) };
        *(uint4*)(Wb2f + (size_t)t * 8) = p;
    } else {
        if (threadIdx.x < 32) {
            uint4 z = {0u, 0u, 0u, 0u};
            *(uint4*)(y2 + (size_t)N_NODES_C * 256 + threadIdx.x * 8) = z;
        }
    }
}

// ---- Kernel A: 64-row tile. out[64,0:256] = x@W1^T + b (fp32 -> d_out),
// ----           y2[64,0:256] = x@W2^T (bf16 -> ws). 512 thr = 8 waves,
// ----           wave w owns 64 output cols x all four 16-row strips.
__global__ __launch_bounds__(512, 4) void gemm_xw_kernel(
    const float* __restrict__ x, const ushort* __restrict__ Wb2f,
    const float* __restrict__ bias, ushort* __restrict__ y2,
    float* __restrict__ out)
{
    __shared__ ushort sA[BM * LDS_A_STRIDE];   // 33,792 B

    const int tid = threadIdx.x;
    const int node0 = blockIdx.x * BM;

    // stage x tile -> bf16 LDS: 64 rows x 256 cols; 4 iters x 512 thr,
    // each thread converts 8 floats (32B load -> 16B LDS write)
    {
        #pragma unroll
        for (int it = 0; it < 4; ++it) {
            const int idx = it * 512 + tid;       // 8-float chunk id
            const int row = idx >> 5;             // 0..63
            const int c8  = idx & 31;             // chunk in row
            const int rg  = node0 + row;
            const float* src = x + (size_t)(rg < N_NODES_C ? rg : N_NODES_C - 1) * D_IN + c8 * 8;
            float4 v0 = ((const float4*)src)[0];
            float4 v1 = ((const float4*)src)[1];
            uint4 p = { pack2(v0.x, v0.y), pack2(v0.z, v0.w),
                        pack2(v1.x, v1.y), pack2(v1.z, v1.w) };
            *(uint4*)(sA + (size_t)row * LDS_A_STRIDE + c8 * 8) = p;
        }
    }
    __syncthreads();

    const int w = tid >> 6;              // 0..7 -> 64-col slice
    const int lane = tid & 63;
    const int quad = lane >> 4;
    const int r16  = lane & 15;

    f32x4 acc[4][4];                     // [row strip][col frag]
    #pragma unroll
    for (int s = 0; s < 4; ++s)
        #pragma unroll
        for (int j = 0; j < 4; ++j)
            acc[s][j] = (f32x4){0.f, 0.f, 0.f, 0.f};

    const ushort* ap = sA + (size_t)r16 * LDS_A_STRIDE + quad * 8;
    const ushort* bp = Wb2f + ((size_t)(w * 4) * 8 + 0) * 64 * 8 + lane * 8;

    #pragma unroll
    for (int ks = 0; ks < D_IN / 32; ++ks) {
        bf16x8 a0 = *(const bf16x8*)(ap + 0  * 16 * LDS_A_STRIDE + ks * 32);
        bf16x8 a1 = *(const bf16x8*)(ap + 1  * 16 * LDS_A_STRIDE + ks * 32);
        bf16x8 a2 = *(const bf16x8*)(ap + 2  * 16 * LDS_A_STRIDE + ks * 32);
        bf16x8 a3 = *(const bf16x8*)(ap + 3  * 16 * LDS_A_STRIDE + ks * 32);
        #pragma unroll
        for (int j = 0; j < 4; ++j) {
            // cg = w*4 + j; contiguous 1KB per wave-load
            bf16x8 b = *(const bf16x8*)(bp + ((size_t)j * 8 + ks) * 64 * 8);
            acc[0][j] = __builtin_amdgcn_mfma_f32_16x16x32_bf16(a0, b, acc[0][j], 0, 0, 0);
            acc[1][j] = __builtin_amdgcn_mfma_f32_16x16x32_bf16(a1, b, acc[1][j], 0, 0, 0);
            acc[2][j] = __builtin_amdgcn_mfma_f32_16x16x32_bf16(a2, b, acc[2][j], 0, 0, 0);
            acc[3][j] = __builtin_amdgcn_mfma_f32_16x16x32_bf16(a3, b, acc[3][j], 0, 0, 0);
        }
    }

    // D layout: col = lane&15 (-> c), row = quad*4 + reg
    if (w < 4) {   // cols 0..255: self term + bias -> out (fp32)
        #pragma unroll
        for (int j = 0; j < 4; ++j) {
            const int c = w * 64 + j * 16 + r16;
            const float bv = bias[c];
            #pragma unroll
            for (int s = 0; s < 4; ++s)
                #pragma unroll
                for (int r = 0; r < 4; ++r) {
                    const int row = node0 + s * 16 + quad * 4 + r;
                    if (row < N_NODES_C)
                        out[(size_t)row * D_OUT + c] = acc[s][j][r] + bv;
                }
        }
    } else {       // cols 256..511: neighbor-basis term -> y2 (bf16)
        #pragma unroll
        for (int j = 0; j < 4; ++j) {
            const int c2 = (w - 4) * 64 + j * 16 + r16;
            #pragma unroll
            for (int s = 0; s < 4; ++s)
                #pragma unroll
                for (int r = 0; r < 4; ++r) {
                    const int row = node0 + s * 16 + quad * 4 + r;
                    if (row < N_NODES_C)
                        y2[(size_t)row * 256 + c2] = (ushort)f2bf(acc[s][j][r]);
                }
        }
    }
}

// ---- Kernel B: one node per wave. out[i] += inv_deg * sum_d y2[e_d].
// 8 staged dwordx4 gathers per wave (each covers 2 neighbor rows: lanes
// 0..31 -> even d, 32..63 -> odd d), cross-half combine via shfl_xor(32).
// Empty-asm pins keep all 8 gathers + the out-row prefetch in flight.
#define KEEPU4(v) asm volatile("" : "+v"(v.x), "+v"(v.y), "+v"(v.z), "+v"(v.w))
#define KEEPF4(v) asm volatile("" : "+v"(v.x), "+v"(v.y), "+v"(v.z), "+v"(v.w))

__global__ __launch_bounds__(256, 6) void gather_add_kernel(
    const ushort* __restrict__ y2, const int* __restrict__ edge,
    float* __restrict__ out)
{
    const int i = blockIdx.x * 4 + (threadIdx.x >> 6);   // node, 0..99999
    const int lane = threadIdx.x & 63;

    const int e = edge[(size_t)i * MAX_DEG + (lane & 15)];
    const unsigned long long vm = __ballot(e >= 0);
    const int deg = (int)__popcll(vm & 0xFFFFull);       // >= 1
    const float inv = 1.0f / (float)deg;

    const uint32_t off_me = (uint32_t)(e < 0 ? N_NODES_C : e) * 512u;  // row bytes
    const char* yb = (const char*)y2;
    const uint32_t coff = (uint32_t)((lane & 31) * 16);  // 16B slot within 512B row

    // offsets for the 8 paired-row loads
    uint32_t off[8];
    #pragma unroll
    for (int k = 0; k < 8; ++k)
        off[k] = (uint32_t)__shfl((int)off_me, 2 * k + (lane >> 5), 64);

    // prefetch the out row (independent of the gathers)
    const int cw = (lane & 31) * 8 + (lane >> 5) * 4;
    float4 yv = *(const float4*)(out + (size_t)i * D_OUT + cw);

    // stage all 8 gathers
    uint4 g[8];
    #pragma unroll
    for (int k = 0; k < 8; ++k)
        g[k] = *(const uint4*)(yb + (size_t)(off[k] + coff));

    // pin everything live: forces all 9 loads issued before any consume
    KEEPF4(yv);
    #pragma unroll
    for (int k = 0; k < 8; ++k) KEEPU4(g[k]);

    float a[8];
    #pragma unroll
    for (int q = 0; q < 8; ++q) a[q] = 0.f;
    #pragma unroll
    for (int k = 0; k < 8; ++k) {
        uint32_t u[4] = { g[k].x, g[k].y, g[k].z, g[k].w };
        #pragma unroll
        for (int q = 0; q < 4; ++q) {
            union { uint32_t ui; float f; } lo, hi;
            lo.ui = u[q] << 16;
            hi.ui = u[q] & 0xFFFF0000u;
            a[2*q]   += lo.f;
            a[2*q+1] += hi.f;
        }
    }
    // combine even-d half (lanes<32) with odd-d half (lanes>=32)
    #pragma unroll
    for (int q = 0; q < 8; ++q) a[q] += __shfl_xor(a[q], 32, 64);

    // lane writes 4 floats: cols (lane&31)*8 + (lane>>5)*4 + {0..3}
    const int q0 = (lane >> 5) * 4;
    float4 r;
    r.x = yv.x + inv * a[q0 + 0];
    r.y = yv.y + inv * a[q0 + 1];
    r.z = yv.z + inv * a[q0 + 2];
    r.w = yv.w + inv * a[q0 + 3];
    *(float4*)(out + (size_t)i * D_OUT + cw) = r;
}

// ---------------- fallback (small ws): fp32-gather path ----------------
#define D_K 512
#define LDS_STRIDE 520

__global__ __launch_bounds__(256) void cast_w_kernel(const float* __restrict__ W,
                                                     ushort* __restrict__ Wb) {
    int i = (blockIdx.x * 256 + threadIdx.x) * 4;
    float4 v = *(const float4*)(W + i);
    ushort4 p = { (ushort)f2bf(v.x), (ushort)f2bf(v.y),
                  (ushort)f2bf(v.z), (ushort)f2bf(v.w) };
    *(ushort4*)(Wb + i) = p;
}

__global__ __launch_bounds__(256) void sage_fp32_kernel(
    const float* __restrict__ x, const int* __restrict__ edge,
    const ushort* __restrict__ Wb, const float* __restrict__ bias,
    float* __restrict__ out)
{
    __shared__ ushort sH[32 * LDS_STRIDE];
    const int tid = threadIdx.x;
    const int node0 = blockIdx.x * 32;
    {
        const int m = tid >> 3, l = tid & 7;
        const int node = node0 + m;
        const float4* xrow = (const float4*)(x + (size_t)node * D_IN);
        ushort* dst = sH + m * LDS_STRIDE + l * 32;
        #pragma unroll
        for (int q = 0; q < 8; ++q) {
            float4 v = xrow[l * 8 + q];
            ushort4 p = { (ushort)f2bf(v.x), (ushort)f2bf(v.y),
                          (ushort)f2bf(v.z), (ushort)f2bf(v.w) };
            *(ushort4*)(dst + q * 4) = p;
        }
        float4 agg[8];
        #pragma unroll
        for (int q = 0; q < 8; ++q) agg[q] = make_float4(0.f,0.f,0.f,0.f);
        int deg = 0;
        for (int d = 0; d < MAX_DEG; ++d) {
            int nb = edge[(size_t)node * MAX_DEG + d];
            if (nb >= 0) {
                ++deg;
                const float4* nr = (const float4*)(x + (size_t)nb * D_IN);
                #pragma unroll
                for (int q = 0; q < 8; ++q) {
                    float4 t = nr[l * 8 + q];
                    agg[q].x += t.x; agg[q].y += t.y;
                    agg[q].z += t.z; agg[q].w += t.w;
                }
            }
        }
        const float inv = 1.0f / (float)deg;
        ushort* dst2 = sH + m * LDS_STRIDE + D_IN + l * 32;
        #pragma unroll
        for (int q = 0; q < 8; ++q) {
            ushort4 p = { (ushort)f2bf(agg[q].x*inv), (ushort)f2bf(agg[q].y*inv),
                          (ushort)f2bf(agg[q].z*inv), (ushort)f2bf(agg[q].w*inv) };
            *(ushort4*)(dst2 + q * 4) = p;
        }
    }
    __syncthreads();
    {
        const int wave = tid >> 6, lane = tid & 63;
        const int quad = lane >> 4, r16 = lane & 15;
        const int mt = wave & 1, nh = wave >> 1;
        f32x4 acc[8];
        #pragma unroll
        for (int j = 0; j < 8; ++j) {
            float bv = bias[(nh * 8 + j) * 16 + r16];
            acc[j] = (f32x4){bv, bv, bv, bv};
        }
        const ushort* arow = sH + (mt * 16 + r16) * LDS_STRIDE + quad * 8;
        #pragma unroll
        for (int ks = 0; ks < D_K / 32; ++ks) {
            bf16x8 a = *(const bf16x8*)(arow + ks * 32);
            #pragma unroll
            for (int j = 0; j < 8; ++j) {
                const int o = (nh * 8 + j) * 16 + r16;
                bf16x8 b = *(const bf16x8*)(Wb + (size_t)o * D_K + ks * 32 + quad * 8);
                acc[j] = __builtin_amdgcn_mfma_f32_16x16x32_bf16(a, b, acc[j], 0, 0, 0);
            }
        }
        #pragma unroll
        for (int j = 0; j < 8; ++j) {
            const int o = (nh * 8 + j) * 16 + r16;
            #pragma unroll
            for (int r = 0; r < 4; ++r) {
                const int row = node0 + mt * 16 + quad * 4 + r;
                out[(size_t)row * D_OUT + o] = acc[j][r];
            }
        }
    }
}

extern "C" void kernel_launch(void* const* d_in, const int* in_sizes, int n_in,
                              void* d_out, int out_size, void* d_ws, size_t ws_size,
                              hipStream_t stream) {
    const float* x    = (const float*)d_in[0];
    const int*   edge = (const int*)d_in[1];
    const float* W    = (const float*)d_in[2];
    const float* bias = (const float*)d_in[3];
    float* out = (float*)d_out;

    const size_t y2_bytes = (size_t)(N_NODES_C + 1) * 256 * 2;    // 51,200,512
    const size_t wb_bytes = (size_t)512 * 256 * 2;                // 262,144
    const int n = in_sizes[0] / D_IN;                             // 100000

    if (ws_size >= y2_bytes + wb_bytes) {
        ushort* y2   = (ushort*)d_ws;
        ushort* Wb2f = (ushort*)((char*)d_ws + y2_bytes);
        cast_w2f_kernel<<<65, 256, 0, stream>>>(W, Wb2f, y2);
        gemm_xw_kernel<<<(n + BM - 1) / BM, 512, 0, stream>>>(x, Wb2f, bias, y2, out);
        gather_add_kernel<<<n / 4, 256, 0, stream>>>(y2, edge, out);
    } else {
        ushort* Wb = (ushort*)d_ws;     // 256 KB
        cast_w_kernel<<<(D_OUT * D_K) / 1024, 256, 0, stream>>>(W, Wb);
        sage_fp32_kernel<<<n / 32, 256, 0, stream>>>(x, edge, Wb, bias, out);
    }
}

// Round 6
// 382.219 us; speedup vs baseline: 1.0009x; 1.0009x over previous
//
#include <hip/hip_runtime.h>
#include <stdint.h>

// SAGEConv via linearity: out = x@W1^T + b + mean_neigh(x)@W2^T
//                             = [x@W1^T + b] + mean_d( (x@W2^T)[e_d] )
// N=100000, MAX_DEG=16, D_IN=256, D_OUT=256
//
// R9: R7/R8 (single asm with vector-tuple operands) hit "container failed
// twice" both times; R6 (separate scalar pins) ran. Same single-pin
// semantics, scalar operands: ONE asm volatile consuming all 32 gather
// components + 4 out-prefetch components -> all 9 loads issued before one
// waitcnt, compiler cannot sink loads individually (R6's failure mode).

#define MAX_DEG 16
#define D_IN 256
#define D_OUT 256
#define N_NODES_C 100000
#define BM 64
#define LDS_A_STRIDE 264   // 256 + 8 pad (ushort elems); row stride 528 B

typedef __attribute__((ext_vector_type(8))) short bf16x8;   // 8 bf16 = 4 VGPRs
typedef __attribute__((ext_vector_type(4))) float f32x4;

__device__ __forceinline__ uint32_t f2bf(float f) {
    union { float f; uint32_t u; } v; v.f = f;
    uint32_t u = v.u;
    return (u + 0x7FFFu + ((u >> 16) & 1u)) >> 16;   // RNE; inputs finite
}
__device__ __forceinline__ uint32_t pack2(float lo, float hi) {
    return f2bf(lo) | (f2bf(hi) << 16);
}

// ---- cast W into fragment-major bf16 Wb2f[cg][ks][lane][8]:
//      c = cg*16 + (lane&15), k = ks*32 + (lane>>4)*8 + e
//      (c<256 -> W[c][k] self half; c>=256 -> W[c-256][256+k] neighbor half)
// ---- and zero y2 row N (padding row for edge index -1)
__global__ __launch_bounds__(256) void cast_w2f_kernel(
    const float* __restrict__ W, ushort* __restrict__ Wb2f, ushort* __restrict__ y2)
{
    if (blockIdx.x < 64) {
        const int t = blockIdx.x * 256 + threadIdx.x;   // 0..16383
        const int cg   = t >> 9;          // 0..31
        const int ks   = (t >> 6) & 7;    // 0..7
        const int lane = t & 63;
        const int quad = lane >> 4, r16 = lane & 15;
        const int c = cg * 16 + r16;      // 0..511
        const int k = ks * 32 + quad * 8;
        const float* src = W + (size_t)(c & 255) * 512 + (c >> 8) * 256 + k;
        float4 v0 = ((const float4*)src)[0];
        float4 v1 = ((const float4*)src)[1];
        uint4 p = { pack2(v0.x, v0.y), pack2(v0.z, v0.w),
                    pack2(v1.x, v1.y), pack2(v1.z, v1.w) };
        *(uint4*)(Wb2f + (size_t)t * 8) = p;
    } else {
        if (threadIdx.x < 32) {
            uint4 z = {0u, 0u, 0u, 0u};
            *(uint4*)(y2 + (size_t)N_NODES_C * 256 + threadIdx.x * 8) = z;
        }
    }
}

// ---- Kernel A: 64-row tile. out[64,0:256] = x@W1^T + b (fp32 -> d_out),
// ----           y2[64,0:256] = x@W2^T (bf16 -> ws). 512 thr = 8 waves,
// ----           wave w owns 64 output cols x all four 16-row strips.
__global__ __launch_bounds__(512, 4) void gemm_xw_kernel(
    const float* __restrict__ x, const ushort* __restrict__ Wb2f,
    const float* __restrict__ bias, ushort* __restrict__ y2,
    float* __restrict__ out)
{
    __shared__ ushort sA[BM * LDS_A_STRIDE];   // 33,792 B

    const int tid = threadIdx.x;
    const int node0 = blockIdx.x * BM;

    // stage x tile -> bf16 LDS: 64 rows x 256 cols; 4 iters x 512 thr,
    // each thread converts 8 floats (32B load -> 16B LDS write)
    {
        #pragma unroll
        for (int it = 0; it < 4; ++it) {
            const int idx = it * 512 + tid;       // 8-float chunk id
            const int row = idx >> 5;             // 0..63
            const int c8  = idx & 31;             // chunk in row
            const int rg  = node0 + row;
            const float* src = x + (size_t)(rg < N_NODES_C ? rg : N_NODES_C - 1) * D_IN + c8 * 8;
            float4 v0 = ((const float4*)src)[0];
            float4 v1 = ((const float4*)src)[1];
            uint4 p = { pack2(v0.x, v0.y), pack2(v0.z, v0.w),
                        pack2(v1.x, v1.y), pack2(v1.z, v1.w) };
            *(uint4*)(sA + (size_t)row * LDS_A_STRIDE + c8 * 8) = p;
        }
    }
    __syncthreads();

    const int w = tid >> 6;              // 0..7 -> 64-col slice
    const int lane = tid & 63;
    const int quad = lane >> 4;
    const int r16  = lane & 15;

    f32x4 acc[4][4];                     // [row strip][col frag]
    #pragma unroll
    for (int s = 0; s < 4; ++s)
        #pragma unroll
        for (int j = 0; j < 4; ++j)
            acc[s][j] = (f32x4){0.f, 0.f, 0.f, 0.f};

    const ushort* ap = sA + (size_t)r16 * LDS_A_STRIDE + quad * 8;
    const ushort* bp = Wb2f + ((size_t)(w * 4) * 8 + 0) * 64 * 8 + lane * 8;

    #pragma unroll
    for (int ks = 0; ks < D_IN / 32; ++ks) {
        bf16x8 a0 = *(const bf16x8*)(ap + 0  * 16 * LDS_A_STRIDE + ks * 32);
        bf16x8 a1 = *(const bf16x8*)(ap + 1  * 16 * LDS_A_STRIDE + ks * 32);
        bf16x8 a2 = *(const bf16x8*)(ap + 2  * 16 * LDS_A_STRIDE + ks * 32);
        bf16x8 a3 = *(const bf16x8*)(ap + 3  * 16 * LDS_A_STRIDE + ks * 32);
        #pragma unroll
        for (int j = 0; j < 4; ++j) {
            // cg = w*4 + j; contiguous 1KB per wave-load
            bf16x8 b = *(const bf16x8*)(bp + ((size_t)j * 8 + ks) * 64 * 8);
            acc[0][j] = __builtin_amdgcn_mfma_f32_16x16x32_bf16(a0, b, acc[0][j], 0, 0, 0);
            acc[1][j] = __builtin_amdgcn_mfma_f32_16x16x32_bf16(a1, b, acc[1][j], 0, 0, 0);
            acc[2][j] = __builtin_amdgcn_mfma_f32_16x16x32_bf16(a2, b, acc[2][j], 0, 0, 0);
            acc[3][j] = __builtin_amdgcn_mfma_f32_16x16x32_bf16(a3, b, acc[3][j], 0, 0, 0);
        }
    }

    // D layout: col = lane&15 (-> c), row = quad*4 + reg
    if (w < 4) {   // cols 0..255: self term + bias -> out (fp32)
        #pragma unroll
        for (int j = 0; j < 4; ++j) {
            const int c = w * 64 + j * 16 + r16;
            const float bv = bias[c];
            #pragma unroll
            for (int s = 0; s < 4; ++s)
                #pragma unroll
                for (int r = 0; r < 4; ++r) {
                    const int row = node0 + s * 16 + quad * 4 + r;
                    if (row < N_NODES_C)
                        out[(size_t)row * D_OUT + c] = acc[s][j][r] + bv;
                }
        }
    } else {       // cols 256..511: neighbor-basis term -> y2 (bf16)
        #pragma unroll
        for (int j = 0; j < 4; ++j) {
            const int c2 = (w - 4) * 64 + j * 16 + r16;
            #pragma unroll
            for (int s = 0; s < 4; ++s)
                #pragma unroll
                for (int r = 0; r < 4; ++r) {
                    const int row = node0 + s * 16 + quad * 4 + r;
                    if (row < N_NODES_C)
                        y2[(size_t)row * 256 + c2] = (ushort)f2bf(acc[s][j][r]);
                }
        }
    }
}

// ---- Kernel B: one node per wave. out[i] += inv_deg * sum_d y2[e_d].
// 8 staged dwordx4 gathers per wave (each covers 2 neighbor rows: lanes
// 0..31 -> even d, 32..63 -> odd d), cross-half combine via shfl_xor(32).
// ONE asm (scalar operands) pins all 8 gathers + out prefetch live at a
// single point -> all 9 loads issued before one waitcnt.
__global__ __launch_bounds__(256, 6) void gather_add_kernel(
    const ushort* __restrict__ y2, const int* __restrict__ edge,
    float* __restrict__ out)
{
    const int i = blockIdx.x * 4 + (threadIdx.x >> 6);   // node, 0..99999
    const int lane = threadIdx.x & 63;

    const int e = edge[(size_t)i * MAX_DEG + (lane & 15)];
    const unsigned long long vm = __ballot(e >= 0);
    const int deg = (int)__popcll(vm & 0xFFFFull);       // >= 1
    const float inv = 1.0f / (float)deg;

    const uint32_t off_me = (uint32_t)(e < 0 ? N_NODES_C : e) * 512u;  // row bytes
    const char* yb = (const char*)y2;
    const uint32_t coff = (uint32_t)((lane & 31) * 16);  // 16B slot within 512B row

    // offsets for the 8 paired-row loads
    uint32_t off[8];
    #pragma unroll
    for (int k = 0; k < 8; ++k)
        off[k] = (uint32_t)__shfl((int)off_me, 2 * k + (lane >> 5), 64);

    // prefetch the out row (independent of the gathers)
    const int cw = (lane & 31) * 8 + (lane >> 5) * 4;
    float* op = out + (size_t)i * D_OUT + cw;
    float4 yv = *(const float4*)op;

    // stage all 8 gathers
    uint4 g[8];
    #pragma unroll
    for (int k = 0; k < 8; ++k)
        g[k] = *(const uint4*)(yb + (size_t)(off[k] + coff));

    // single pin point: every staged component is an input to ONE asm ->
    // all loads must be issued before it; scheduler can't sink them singly
    asm volatile("" ::
        "v"(g[0].x), "v"(g[0].y), "v"(g[0].z), "v"(g[0].w),
        "v"(g[1].x), "v"(g[1].y), "v"(g[1].z), "v"(g[1].w),
        "v"(g[2].x), "v"(g[2].y), "v"(g[2].z), "v"(g[2].w),
        "v"(g[3].x), "v"(g[3].y), "v"(g[3].z), "v"(g[3].w),
        "v"(g[4].x), "v"(g[4].y), "v"(g[4].z), "v"(g[4].w),
        "v"(g[5].x), "v"(g[5].y), "v"(g[5].z), "v"(g[5].w),
        "v"(g[6].x), "v"(g[6].y), "v"(g[6].z), "v"(g[6].w),
        "v"(g[7].x), "v"(g[7].y), "v"(g[7].z), "v"(g[7].w),
        "v"(yv.x),  "v"(yv.y),  "v"(yv.z),  "v"(yv.w));

    float a[8];
    #pragma unroll
    for (int q = 0; q < 8; ++q) a[q] = 0.f;
    #pragma unroll
    for (int k = 0; k < 8; ++k) {
        uint32_t u[4] = { g[k].x, g[k].y, g[k].z, g[k].w };
        #pragma unroll
        for (int q = 0; q < 4; ++q) {
            union { uint32_t ui; float f; } lo, hi;
            lo.ui = u[q] << 16;
            hi.ui = u[q] & 0xFFFF0000u;
            a[2*q]   += lo.f;
            a[2*q+1] += hi.f;
        }
    }
    // combine even-d half (lanes<32) with odd-d half (lanes>=32)
    #pragma unroll
    for (int q = 0; q < 8; ++q) a[q] += __shfl_xor(a[q], 32, 64);

    // lane writes 4 floats: cols (lane&31)*8 + (lane>>5)*4 + {0..3}
    const int q0 = (lane >> 5) * 4;
    float4 r;
    r.x = yv.x + inv * a[q0 + 0];
    r.y = yv.y + inv * a[q0 + 1];
    r.z = yv.z + inv * a[q0 + 2];
    r.w = yv.w + inv * a[q0 + 3];
    *(float4*)op = r;
}

// ---------------- fallback (small ws): fp32-gather path ----------------
#define D_K 512
#define LDS_STRIDE 520

__global__ __launch_bounds__(256) void cast_w_kernel(const float* __restrict__ W,
                                                     ushort* __restrict__ Wb) {
    int i = (blockIdx.x * 256 + threadIdx.x) * 4;
    float4 v = *(const float4*)(W + i);
    ushort4 p = { (ushort)f2bf(v.x), (ushort)f2bf(v.y),
                  (ushort)f2bf(v.z), (ushort)f2bf(v.w) };
    *(ushort4*)(Wb + i) = p;
}

__global__ __launch_bounds__(256) void sage_fp32_kernel(
    const float* __restrict__ x, const int* __restrict__ edge,
    const ushort* __restrict__ Wb, const float* __restrict__ bias,
    float* __restrict__ out)
{
    __shared__ ushort sH[32 * LDS_STRIDE];
    const int tid = threadIdx.x;
    const int node0 = blockIdx.x * 32;
    {
        const int m = tid >> 3, l = tid & 7;
        const int node = node0 + m;
        const float4* xrow = (const float4*)(x + (size_t)node * D_IN);
        ushort* dst = sH + m * LDS_STRIDE + l * 32;
        #pragma unroll
        for (int q = 0; q < 8; ++q) {
            float4 v = xrow[l * 8 + q];
            ushort4 p = { (ushort)f2bf(v.x), (ushort)f2bf(v.y),
                          (ushort)f2bf(v.z), (ushort)f2bf(v.w) };
            *(ushort4*)(dst + q * 4) = p;
        }
        float4 agg[8];
        #pragma unroll
        for (int q = 0; q < 8; ++q) agg[q] = make_float4(0.f,0.f,0.f,0.f);
        int deg = 0;
        for (int d = 0; d < MAX_DEG; ++d) {
            int nb = edge[(size_t)node * MAX_DEG + d];
            if (nb >= 0) {
                ++deg;
                const float4* nr = (const float4*)(x + (size_t)nb * D_IN);
                #pragma unroll
                for (int q = 0; q < 8; ++q) {
                    float4 t = nr[l * 8 + q];
                    agg[q].x += t.x; agg[q].y += t.y;
                    agg[q].z += t.z; agg[q].w += t.w;
                }
            }
        }
        const float inv = 1.0f / (float)deg;
        ushort* dst2 = sH + m * LDS_STRIDE + D_IN + l * 32;
        #pragma unroll
        for (int q = 0; q < 8; ++q) {
            ushort4 p = { (ushort)f2bf(agg[q].x*inv), (ushort)f2bf(agg[q].y*inv),
                          (ushort)f2bf(agg[q].z*inv), (ushort)f2bf(agg[q].w*inv) };
            *(ushort4*)(dst2 + q * 4) = p;
        }
    }
    __syncthreads();
    {
        const int wave = tid >> 6, lane = tid & 63;
        const int quad = lane >> 4, r16 = lane & 15;
        const int mt = wave & 1, nh = wave >> 1;
        f32x4 acc[8];
        #pragma unroll
        for (int j = 0; j < 8; ++j) {
            float bv = bias[(nh * 8 + j) * 16 + r16];
            acc[j] = (f32x4){bv, bv, bv, bv};
        }
        const ushort* arow = sH + (mt * 16 + r16) * LDS_STRIDE + quad * 8;
        #pragma unroll
        for (int ks = 0; ks < D_K / 32; ++ks) {
            bf16x8 a = *(const bf16x8*)(arow + ks * 32);
            #pragma unroll
            for (int j = 0; j < 8; ++j) {
                const int o = (nh * 8 + j) * 16 + r16;
                bf16x8 b = *(const bf16x8*)(Wb + (size_t)o * D_K + ks * 32 + quad * 8);
                acc[j] = __builtin_amdgcn_mfma_f32_16x16x32_bf16(a, b, acc[j], 0, 0, 0);
            }
        }
        #pragma unroll
        for (int j = 0; j < 8; ++j) {
            const int o = (nh * 8 + j) * 16 + r16;
            #pragma unroll
            for (int r = 0; r < 4; ++r) {
                const int row = node0 + mt * 16 + quad * 4 + r;
                out[(size_t)row * D_OUT + o] = acc[j][r];
            }
        }
    }
}

extern "C" void kernel_launch(void* const* d_in, const int* in_sizes, int n_in,
                              void* d_out, int out_size, void* d_ws, size_t ws_size,
                              hipStream_t stream) {
    const float* x    = (const float*)d_in[0];
    const int*   edge = (const int*)d_in[1];
    const float* W    = (const float*)d_in[2];
    const float* bias = (const float*)d_in[3];
    float* out = (float*)d_out;

    const size_t y2_bytes = (size_t)(N_NODES_C + 1) * 256 * 2;    // 51,200,512
    const size_t wb_bytes = (size_t)512 * 256 * 2;                // 262,144
    const int n = in_sizes[0] / D_IN;                             // 100000

    if (ws_size >= y2_bytes + wb_bytes) {
        ushort* y2   = (ushort*)d_ws;
        ushort* Wb2f = (ushort*)((char*)d_ws + y2_bytes);
        cast_w2f_kernel<<<65, 256, 0, stream>>>(W, Wb2f, y2);
        gemm_xw_kernel<<<(n + BM - 1) / BM, 512, 0, stream>>>(x, Wb2f, bias, y2, out);
        gather_add_kernel<<<n / 4, 256, 0, stream>>>(y2, edge, out);
    } else {
        ushort* Wb = (ushort*)d_ws;     // 256 KB
        cast_w_kernel<<<(D_OUT * D_K) / 1024, 256, 0, stream>>>(W, Wb);
        sage_fp32_kernel<<<n / 32, 256, 0, stream>>>(x, edge, Wb, bias, out);
    }
}

// Round 7
// 376.624 us; speedup vs baseline: 1.0158x; 1.0149x over previous
//
#include <hip/hip_runtime.h>
#include <stdint.h>

// SAGEConv via linearity: out = x@W1^T + b + mean_neigh(x)@W2^T
//                             = [x@W1^T + b] + mean_d( (x@W2^T)[e_d] )
// N=100000, MAX_DEG=16, D_IN=256, D_OUT=256
//
// R10: three rounds of VGPR-staging tricks all collapsed (VGPR stuck at 32,
// ~2 gathers in flight, 141us latency-bound). Structural fix: stage gathers
// via global_load_lds (async DMA, NO dest register -> compiler cannot
// re-fuse/serialize). 8x1KB row-pair copies per wave into a private 8KB LDS
// slice, one vmcnt(0), conflict-free ds_read_b128 readback.

#define MAX_DEG 16
#define D_IN 256
#define D_OUT 256
#define N_NODES_C 100000
#define BM 64
#define LDS_A_STRIDE 264   // 256 + 8 pad (ushort elems); row stride 528 B

typedef __attribute__((ext_vector_type(8))) short bf16x8;   // 8 bf16 = 4 VGPRs
typedef __attribute__((ext_vector_type(4))) float f32x4;

typedef const __attribute__((address_space(1))) void* gas_ptr;
typedef __attribute__((address_space(3))) void* las_ptr;

__device__ __forceinline__ uint32_t f2bf(float f) {
    union { float f; uint32_t u; } v; v.f = f;
    uint32_t u = v.u;
    return (u + 0x7FFFu + ((u >> 16) & 1u)) >> 16;   // RNE; inputs finite
}
__device__ __forceinline__ uint32_t pack2(float lo, float hi) {
    return f2bf(lo) | (f2bf(hi) << 16);
}

// ---- cast W into fragment-major bf16 Wb2f[cg][ks][lane][8]:
//      c = cg*16 + (lane&15), k = ks*32 + (lane>>4)*8 + e
//      (c<256 -> W[c][k] self half; c>=256 -> W[c-256][256+k] neighbor half)
// ---- and zero y2 row N (padding row for edge index -1)
__global__ __launch_bounds__(256) void cast_w2f_kernel(
    const float* __restrict__ W, ushort* __restrict__ Wb2f, ushort* __restrict__ y2)
{
    if (blockIdx.x < 64) {
        const int t = blockIdx.x * 256 + threadIdx.x;   // 0..16383
        const int cg   = t >> 9;          // 0..31
        const int ks   = (t >> 6) & 7;    // 0..7
        const int lane = t & 63;
        const int quad = lane >> 4, r16 = lane & 15;
        const int c = cg * 16 + r16;      // 0..511
        const int k = ks * 32 + quad * 8;
        const float* src = W + (size_t)(c & 255) * 512 + (c >> 8) * 256 + k;
        float4 v0 = ((const float4*)src)[0];
        float4 v1 = ((const float4*)src)[1];
        uint4 p = { pack2(v0.x, v0.y), pack2(v0.z, v0.w),
                    pack2(v1.x, v1.y), pack2(v1.z, v1.w) };
        *(uint4*)(Wb2f + (size_t)t * 8) = p;
    } else {
        if (threadIdx.x < 32) {
            uint4 z = {0u, 0u, 0u, 0u};
            *(uint4*)(y2 + (size_t)N_NODES_C * 256 + threadIdx.x * 8) = z;
        }
    }
}

// ---- Kernel A: 64-row tile. out[64,0:256] = x@W1^T + b (fp32 -> d_out),
// ----           y2[64,0:256] = x@W2^T (bf16 -> ws). 512 thr = 8 waves,
// ----           wave w owns 64 output cols x all four 16-row strips.
__global__ __launch_bounds__(512, 4) void gemm_xw_kernel(
    const float* __restrict__ x, const ushort* __restrict__ Wb2f,
    const float* __restrict__ bias, ushort* __restrict__ y2,
    float* __restrict__ out)
{
    __shared__ ushort sA[BM * LDS_A_STRIDE];   // 33,792 B

    const int tid = threadIdx.x;
    const int node0 = blockIdx.x * BM;

    // stage x tile -> bf16 LDS: 64 rows x 256 cols; 4 iters x 512 thr,
    // each thread converts 8 floats (32B load -> 16B LDS write)
    {
        #pragma unroll
        for (int it = 0; it < 4; ++it) {
            const int idx = it * 512 + tid;       // 8-float chunk id
            const int row = idx >> 5;             // 0..63
            const int c8  = idx & 31;             // chunk in row
            const int rg  = node0 + row;
            const float* src = x + (size_t)(rg < N_NODES_C ? rg : N_NODES_C - 1) * D_IN + c8 * 8;
            float4 v0 = ((const float4*)src)[0];
            float4 v1 = ((const float4*)src)[1];
            uint4 p = { pack2(v0.x, v0.y), pack2(v0.z, v0.w),
                        pack2(v1.x, v1.y), pack2(v1.z, v1.w) };
            *(uint4*)(sA + (size_t)row * LDS_A_STRIDE + c8 * 8) = p;
        }
    }
    __syncthreads();

    const int w = tid >> 6;              // 0..7 -> 64-col slice
    const int lane = tid & 63;
    const int quad = lane >> 4;
    const int r16  = lane & 15;

    f32x4 acc[4][4];                     // [row strip][col frag]
    #pragma unroll
    for (int s = 0; s < 4; ++s)
        #pragma unroll
        for (int j = 0; j < 4; ++j)
            acc[s][j] = (f32x4){0.f, 0.f, 0.f, 0.f};

    const ushort* ap = sA + (size_t)r16 * LDS_A_STRIDE + quad * 8;
    const ushort* bp = Wb2f + ((size_t)(w * 4) * 8 + 0) * 64 * 8 + lane * 8;

    #pragma unroll
    for (int ks = 0; ks < D_IN / 32; ++ks) {
        bf16x8 a0 = *(const bf16x8*)(ap + 0  * 16 * LDS_A_STRIDE + ks * 32);
        bf16x8 a1 = *(const bf16x8*)(ap + 1  * 16 * LDS_A_STRIDE + ks * 32);
        bf16x8 a2 = *(const bf16x8*)(ap + 2  * 16 * LDS_A_STRIDE + ks * 32);
        bf16x8 a3 = *(const bf16x8*)(ap + 3  * 16 * LDS_A_STRIDE + ks * 32);
        #pragma unroll
        for (int j = 0; j < 4; ++j) {
            // cg = w*4 + j; contiguous 1KB per wave-load
            bf16x8 b = *(const bf16x8*)(bp + ((size_t)j * 8 + ks) * 64 * 8);
            acc[0][j] = __builtin_amdgcn_mfma_f32_16x16x32_bf16(a0, b, acc[0][j], 0, 0, 0);
            acc[1][j] = __builtin_amdgcn_mfma_f32_16x16x32_bf16(a1, b, acc[1][j], 0, 0, 0);
            acc[2][j] = __builtin_amdgcn_mfma_f32_16x16x32_bf16(a2, b, acc[2][j], 0, 0, 0);
            acc[3][j] = __builtin_amdgcn_mfma_f32_16x16x32_bf16(a3, b, acc[3][j], 0, 0, 0);
        }
    }

    // D layout: col = lane&15 (-> c), row = quad*4 + reg
    if (w < 4) {   // cols 0..255: self term + bias -> out (fp32)
        #pragma unroll
        for (int j = 0; j < 4; ++j) {
            const int c = w * 64 + j * 16 + r16;
            const float bv = bias[c];
            #pragma unroll
            for (int s = 0; s < 4; ++s)
                #pragma unroll
                for (int r = 0; r < 4; ++r) {
                    const int row = node0 + s * 16 + quad * 4 + r;
                    if (row < N_NODES_C)
                        out[(size_t)row * D_OUT + c] = acc[s][j][r] + bv;
                }
        }
    } else {       // cols 256..511: neighbor-basis term -> y2 (bf16)
        #pragma unroll
        for (int j = 0; j < 4; ++j) {
            const int c2 = (w - 4) * 64 + j * 16 + r16;
            #pragma unroll
            for (int s = 0; s < 4; ++s)
                #pragma unroll
                for (int r = 0; r < 4; ++r) {
                    const int row = node0 + s * 16 + quad * 4 + r;
                    if (row < N_NODES_C)
                        y2[(size_t)row * 256 + c2] = (ushort)f2bf(acc[s][j][r]);
                }
        }
    }
}

// ---- Kernel B: one node per wave. out[i] += inv_deg * sum_d y2[e_d].
// 8 async global_load_lds row-pair copies (1KB each) into a private 8KB LDS
// slice -> no dest VGPRs, compiler cannot serialize; one vmcnt(0), then
// conflict-free readback + accumulate. Cross-half combine via shfl_xor(32).
__global__ __launch_bounds__(256, 4) void gather_add_kernel(
    const ushort* __restrict__ y2, const int* __restrict__ edge,
    float* __restrict__ out)
{
    __shared__ char sBuf[4 * 8 * 1024];                  // 32 KB: 4 waves x 8KB

    const int w4   = threadIdx.x >> 6;                   // wave in block
    const int lane = threadIdx.x & 63;
    const int i = blockIdx.x * 4 + w4;                   // node, 0..99999

    const int e = edge[(size_t)i * MAX_DEG + (lane & 15)];
    const unsigned long long vm = __ballot(e >= 0);
    const int deg = (int)__popcll(vm & 0xFFFFull);       // >= 1
    const float inv = 1.0f / (float)deg;

    const uint32_t off_me = (uint32_t)(e < 0 ? N_NODES_C : e) * 512u;  // row bytes
    const char* yb = (const char*)y2;
    const uint32_t coff = (uint32_t)((lane & 31) * 16);  // 16B slot within 512B row

    // prefetch the out row (independent; completes under the same vmcnt wait)
    const int cw = (lane & 31) * 8 + (lane >> 5) * 4;
    float* op = out + (size_t)i * D_OUT + cw;
    float4 yv = *(const float4*)op;

    // issue 8 async row-pair copies: chunk k = rows e_{2k} (lanes 0..31)
    // and e_{2k+1} (lanes 32..63); LDS dest = wavebase + k*1024 + lane*16
    char* lw = sBuf + (size_t)w4 * 8192;
    #pragma unroll
    for (int k = 0; k < 8; ++k) {
        const uint32_t ro = (uint32_t)__shfl((int)off_me, 2 * k + (lane >> 5), 64);
        const char* gsrc = yb + (size_t)(ro + coff);
        __builtin_amdgcn_global_load_lds((gas_ptr)gsrc, (las_ptr)(lw + k * 1024),
                                         16, 0, 0);
    }
    asm volatile("s_waitcnt vmcnt(0)" ::: "memory");
    __builtin_amdgcn_sched_barrier(0);

    float a[8];
    #pragma unroll
    for (int q = 0; q < 8; ++q) a[q] = 0.f;
    #pragma unroll
    for (int k = 0; k < 8; ++k) {
        uint4 g = *(const uint4*)(lw + k * 1024 + lane * 16);
        uint32_t u[4] = { g.x, g.y, g.z, g.w };
        #pragma unroll
        for (int q = 0; q < 4; ++q) {
            union { uint32_t ui; float f; } lo, hi;
            lo.ui = u[q] << 16;
            hi.ui = u[q] & 0xFFFF0000u;
            a[2*q]   += lo.f;
            a[2*q+1] += hi.f;
        }
    }
    // combine even-d half (lanes<32) with odd-d half (lanes>=32)
    #pragma unroll
    for (int q = 0; q < 8; ++q) a[q] += __shfl_xor(a[q], 32, 64);

    // lane writes 4 floats: cols (lane&31)*8 + (lane>>5)*4 + {0..3}
    const int q0 = (lane >> 5) * 4;
    float4 r;
    r.x = yv.x + inv * a[q0 + 0];
    r.y = yv.y + inv * a[q0 + 1];
    r.z = yv.z + inv * a[q0 + 2];
    r.w = yv.w + inv * a[q0 + 3];
    *(float4*)op = r;
}

// ---------------- fallback (small ws): fp32-gather path ----------------
#define D_K 512
#define LDS_STRIDE 520

__global__ __launch_bounds__(256) void cast_w_kernel(const float* __restrict__ W,
                                                     ushort* __restrict__ Wb) {
    int i = (blockIdx.x * 256 + threadIdx.x) * 4;
    float4 v = *(const float4*)(W + i);
    ushort4 p = { (ushort)f2bf(v.x), (ushort)f2bf(v.y),
                  (ushort)f2bf(v.z), (ushort)f2bf(v.w) };
    *(ushort4*)(Wb + i) = p;
}

__global__ __launch_bounds__(256) void sage_fp32_kernel(
    const float* __restrict__ x, const int* __restrict__ edge,
    const ushort* __restrict__ Wb, const float* __restrict__ bias,
    float* __restrict__ out)
{
    __shared__ ushort sH[32 * LDS_STRIDE];
    const int tid = threadIdx.x;
    const int node0 = blockIdx.x * 32;
    {
        const int m = tid >> 3, l = tid & 7;
        const int node = node0 + m;
        const float4* xrow = (const float4*)(x + (size_t)node * D_IN);
        ushort* dst = sH + m * LDS_STRIDE + l * 32;
        #pragma unroll
        for (int q = 0; q < 8; ++q) {
            float4 v = xrow[l * 8 + q];
            ushort4 p = { (ushort)f2bf(v.x), (ushort)f2bf(v.y),
                          (ushort)f2bf(v.z), (ushort)f2bf(v.w) };
            *(ushort4*)(dst + q * 4) = p;
        }
        float4 agg[8];
        #pragma unroll
        for (int q = 0; q < 8; ++q) agg[q] = make_float4(0.f,0.f,0.f,0.f);
        int deg = 0;
        for (int d = 0; d < MAX_DEG; ++d) {
            int nb = edge[(size_t)node * MAX_DEG + d];
            if (nb >= 0) {
                ++deg;
                const float4* nr = (const float4*)(x + (size_t)nb * D_IN);
                #pragma unroll
                for (int q = 0; q < 8; ++q) {
                    float4 t = nr[l * 8 + q];
                    agg[q].x += t.x; agg[q].y += t.y;
                    agg[q].z += t.z; agg[q].w += t.w;
                }
            }
        }
        const float inv = 1.0f / (float)deg;
        ushort* dst2 = sH + m * LDS_STRIDE + D_IN + l * 32;
        #pragma unroll
        for (int q = 0; q < 8; ++q) {
            ushort4 p = { (ushort)f2bf(agg[q].x*inv), (ushort)f2bf(agg[q].y*inv),
                          (ushort)f2bf(agg[q].z*inv), (ushort)f2bf(agg[q].w*inv) };
            *(ushort4*)(dst2 + q * 4) = p;
        }
    }
    __syncthreads();
    {
        const int wave = tid >> 6, lane = tid & 63;
        const int quad = lane >> 4, r16 = lane & 15;
        const int mt = wave & 1, nh = wave >> 1;
        f32x4 acc[8];
        #pragma unroll
        for (int j = 0; j < 8; ++j) {
            float bv = bias[(nh * 8 + j) * 16 + r16];
            acc[j] = (f32x4){bv, bv, bv, bv};
        }
        const ushort* arow = sH + (mt * 16 + r16) * LDS_STRIDE + quad * 8;
        #pragma unroll
        for (int ks = 0; ks < D_K / 32; ++ks) {
            bf16x8 a = *(const bf16x8*)(arow + ks * 32);
            #pragma unroll
            for (int j = 0; j < 8; ++j) {
                const int o = (nh * 8 + j) * 16 + r16;
                bf16x8 b = *(const bf16x8*)(Wb + (size_t)o * D_K + ks * 32 + quad * 8);
                acc[j] = __builtin_amdgcn_mfma_f32_16x16x32_bf16(a, b, acc[j], 0, 0, 0);
            }
        }
        #pragma unroll
        for (int j = 0; j < 8; ++j) {
            const int o = (nh * 8 + j) * 16 + r16;
            #pragma unroll
            for (int r = 0; r < 4; ++r) {
                const int row = node0 + mt * 16 + quad * 4 + r;
                out[(size_t)row * D_OUT + o] = acc[j][r];
            }
        }
    }
}

extern "C" void kernel_launch(void* const* d_in, const int* in_sizes, int n_in,
                              void* d_out, int out_size, void* d_ws, size_t ws_size,
                              hipStream_t stream) {
    const float* x    = (const float*)d_in[0];
    const int*   edge = (const int*)d_in[1];
    const float* W    = (const float*)d_in[2];
    const float* bias = (const float*)d_in[3];
    float* out = (float*)d_out;

    const size_t y2_bytes = (size_t)(N_NODES_C + 1) * 256 * 2;    // 51,200,512
    const size_t wb_bytes = (size_t)512 * 256 * 2;                // 262,144
    const int n = in_sizes[0] / D_IN;                             // 100000

    if (ws_size >= y2_bytes + wb_bytes) {
        ushort* y2   = (ushort*)d_ws;
        ushort* Wb2f = (ushort*)((char*)d_ws + y2_bytes);
        cast_w2f_kernel<<<65, 256, 0, stream>>>(W, Wb2f, y2);
        gemm_xw_kernel<<<(n + BM - 1) / BM, 512, 0, stream>>>(x, Wb2f, bias, y2, out);
        gather_add_kernel<<<n / 4, 256, 0, stream>>>(y2, edge, out);
    } else {
        ushort* Wb = (ushort*)d_ws;     // 256 KB
        cast_w_kernel<<<(D_OUT * D_K) / 1024, 256, 0, stream>>>(W, Wb);
        sage_fp32_kernel<<<n / 32, 256, 0, stream>>>(x, edge, Wb, bias, out);
    }
}